// Round 15
// baseline (118.105 us; speedup 1.0000x reference)
//
#include <hip/hip_runtime.h>

// GCN forward, f32. aggregate(x)@W1 == aggregate(x@W1); single-pass CSR build
// using 16-bit-packed LDS counters (2 nodes per uint, all 50K nodes in 100KB).
// Pipeline (6 launches):
//  K1 k_hist_gemm : blocks [0,64)=in-degree hist (reads dst only),
//                   [64,128)=out-degree hist (reads src only),
//                   [128,..)=gemm y = x @ W1 (8 rows/wave, x via s_load)
//  K2 k_merge_scan: sum 64 chunk partials -> cnts(in|out<<16) + colpref;
//                   block-local exclusive scan of cnt_in -> cursor + bsum
//  K3 k_scan_bsum : exclusive scan of bsum (single block)
//  K4 k_bin       : SINGLE pass, 64 blocks; LDS packed cursor over all nodes;
//                   col[p] = src | cnt_out<<16
//  K5 k_node      : per-node gather of y -> +b1, relu, dot W2 -> zs
//  K6 k_out       : layer-2 scalar gather -> out
// Packing safety: per-chunk per-node counts <= ce=12500 < 2^16 (no carry);
// node ids < 50000 < 2^16; degrees < 2^16. fp16-y stays banned (R11/R12).

constexpr int D = 64;
constexpr int NCHUNK = 64;         // edge chunks
constexpr int HTH = 1024;          // threads for hist/bin/fused blocks

typedef float f32x8 __attribute__((ext_vector_type(8)));

__device__ __forceinline__ int rl_i(int v, int l) { return __builtin_amdgcn_readlane(v, l); }
__device__ __forceinline__ float rl_f(float v, int l) {
    return __builtin_bit_cast(float, __builtin_amdgcn_readlane(__builtin_bit_cast(int, v), l));
}

// K1: fused hist(in) / hist(out) / gemm, partitioned by blockIdx.x
__global__ void __launch_bounds__(HTH) k_hist_gemm(
        const int* __restrict__ src, const int* __restrict__ dst,
        unsigned int* __restrict__ part_in, unsigned int* __restrict__ part_out,
        int e, int ce, int W,
        const float* __restrict__ x, const float* __restrict__ W1,
        float* __restrict__ y, int n) {
    extern __shared__ unsigned int smem[];
    int tid = threadIdx.x;

    if (blockIdx.x < 2 * NCHUNK) {
        // ---- histogram: packed ushort counters, 2 nodes per uint ----
        unsigned int* h = smem;
        int isOut = (blockIdx.x >= NCHUNK) ? 1 : 0;
        int b = blockIdx.x & (NCHUNK - 1);
        const int* key = isOut ? src : dst;
        for (int i = tid; i < W; i += HTH) h[i] = 0u;
        __syncthreads();
        int lo = b * ce, hi = min(lo + ce, e);
        for (int i = lo + tid; i < hi; i += HTH) {
            int v = key[i];
            atomicAdd(&h[v >> 1], (v & 1) ? 0x10000u : 1u);
        }
        __syncthreads();
        unsigned int* p = (isOut ? part_out : part_in) + (size_t)b * W;
        for (int i = tid; i < W; i += HTH) p[i] = h[i];
    } else {
        // ---- gemm: 16 waves x 8 rows = 128 rows per block ----
        float* sW1 = (float*)smem;
        for (int i = tid; i < D * D; i += HTH) sW1[i] = W1[i];
        __syncthreads();

        int lane = tid & 63;
        int wv = __builtin_amdgcn_readfirstlane(tid >> 6);
        int gb = blockIdx.x - 2 * NCHUNK;
        int r0 = (gb * 16 + wv) * 8;
        if (r0 >= n) return;

        float acc[8];
#pragma unroll
        for (int i = 0; i < 8; ++i) acc[i] = 0.0f;

        if (r0 + 8 <= n) {
            const float* xw = x + (size_t)r0 * D;
#pragma unroll
            for (int kt = 0; kt < 8; ++kt) {
                const float* p = xw + kt * 8;
                f32x8 X0, X1, X2, X3, X4, X5, X6, X7;
                asm volatile(
                    "s_load_dwordx8 %0, %8, 0x0\n\t"
                    "s_load_dwordx8 %1, %8, 0x100\n\t"
                    "s_load_dwordx8 %2, %8, 0x200\n\t"
                    "s_load_dwordx8 %3, %8, 0x300\n\t"
                    "s_load_dwordx8 %4, %8, 0x400\n\t"
                    "s_load_dwordx8 %5, %8, 0x500\n\t"
                    "s_load_dwordx8 %6, %8, 0x600\n\t"
                    "s_load_dwordx8 %7, %8, 0x700\n\t"
                    "s_waitcnt lgkmcnt(0)"
                    : "=s"(X0), "=s"(X1), "=s"(X2), "=s"(X3),
                      "=s"(X4), "=s"(X5), "=s"(X6), "=s"(X7)
                    : "s"(p));
#pragma unroll
                for (int j = 0; j < 8; ++j) {
                    float wk = sW1[(kt * 8 + j) * D + lane];
                    acc[0] = fmaf(X0[j], wk, acc[0]);
                    acc[1] = fmaf(X1[j], wk, acc[1]);
                    acc[2] = fmaf(X2[j], wk, acc[2]);
                    acc[3] = fmaf(X3[j], wk, acc[3]);
                    acc[4] = fmaf(X4[j], wk, acc[4]);
                    acc[5] = fmaf(X5[j], wk, acc[5]);
                    acc[6] = fmaf(X6[j], wk, acc[6]);
                    acc[7] = fmaf(X7[j], wk, acc[7]);
                }
            }
#pragma unroll
            for (int i = 0; i < 8; ++i)
                y[(size_t)(r0 + i) * D + lane] = acc[i];
        } else {
            // tail (never taken for n % 8 == 0)
            float xr[8];
#pragma unroll
            for (int i = 0; i < 8; ++i) {
                int r = r0 + i;
                xr[i] = (r < n) ? x[(size_t)r * D + lane] : 0.0f;
            }
#pragma unroll
            for (int k = 0; k < D; ++k) {
                float wk = sW1[k * D + lane];
#pragma unroll
                for (int i = 0; i < 8; ++i)
                    acc[i] = fmaf(rl_f(xr[i], k), wk, acc[i]);
            }
#pragma unroll
            for (int i = 0; i < 8; ++i) {
                int r = r0 + i;
                if (r < n) y[(size_t)r * D + lane] = acc[i];
            }
        }
    }
}

// K2: per node v, sum chunk partials -> cnts + colpref prefix; block scan of
// cnt_in -> cursor(partial) + bsum
__global__ void k_merge_scan(const unsigned int* __restrict__ part_in,
                             const unsigned int* __restrict__ part_out,
                             unsigned short* __restrict__ colpref,
                             unsigned int* __restrict__ cnts,
                             int* __restrict__ cursor, int* __restrict__ bsum,
                             int n, int W) {
    __shared__ int s[256];
    int tid = threadIdx.x;
    int v = blockIdx.x * 256 + tid;
    int ci = 0;
    if (v < n) {
        int sh = (v & 1) * 16;
        size_t w = (size_t)(v >> 1);
        unsigned int run_in = 0, tout = 0;
        for (int b = 0; b < NCHUNK; ++b) {
            colpref[(size_t)b * n + v] = (unsigned short)run_in;
            run_in += (part_in[(size_t)b * W + w] >> sh) & 0xFFFFu;
            tout   += (part_out[(size_t)b * W + w] >> sh) & 0xFFFFu;
        }
        ci = (int)run_in;
        cnts[v] = run_in | (tout << 16);
    }
    s[tid] = ci;
    __syncthreads();
#pragma unroll
    for (int off = 1; off < 256; off <<= 1) {
        int t = (tid >= off) ? s[tid - off] : 0;
        __syncthreads();
        s[tid] += t;
        __syncthreads();
    }
    if (v < n) cursor[v] = s[tid] - ci;
    if (tid == 255) bsum[blockIdx.x] = s[255];
}

__global__ void k_scan_bsum(int* __restrict__ bsum, int nb) {
    __shared__ int s[256];
    __shared__ int carry;
    int tid = threadIdx.x;
    if (tid == 0) carry = 0;
    __syncthreads();
    for (int start = 0; start < nb; start += 256) {
        int i = start + tid;
        int v = (i < nb) ? bsum[i] : 0;
        s[tid] = v;
        __syncthreads();
#pragma unroll
        for (int off = 1; off < 256; off <<= 1) {
            int t = (tid >= off) ? s[tid - off] : 0;
            __syncthreads();
            s[tid] += t;
            __syncthreads();
        }
        if (i < nb) bsum[i] = s[tid] - v + carry;
        __syncthreads();
        if (tid == 0) carry += s[255];
        __syncthreads();
    }
}

// K4: single-pass bin; LDS = packed per-node local cursors (init = colpref[b]);
// p = cursor[d] + bsum[d>>8] + local_offset
__global__ void __launch_bounds__(HTH) k_bin(
        const int* __restrict__ src, const int* __restrict__ dst,
        const int* __restrict__ cursor, const int* __restrict__ bsum,
        const unsigned short* __restrict__ colpref,
        const unsigned int* __restrict__ cnts,
        unsigned int* __restrict__ col, int e, int n, int ce, int W) {
    extern __shared__ unsigned int cur[];
    int b = blockIdx.x;
    const unsigned int* cp = (const unsigned int*)(colpref + (size_t)b * n);
    for (int i = threadIdx.x; i < W; i += HTH) cur[i] = cp[i];
    __syncthreads();
    int lo = b * ce, hi = min(lo + ce, e);
    for (int i = lo + threadIdx.x; i < hi; i += HTH) {
        int d = dst[i];
        int s2 = src[i];
        unsigned int old = atomicAdd(&cur[d >> 1], (d & 1) ? 0x10000u : 1u);
        int pl = (int)((old >> ((d & 1) * 16)) & 0xFFFFu);
        int p = cursor[d] + bsum[d >> 8] + pl;
        col[p] = (unsigned int)s2 | (cnts[s2] & 0xFFFF0000u);
    }
}

// K5: one wave per node (grid-stride); all loads coalesced
__global__ void __launch_bounds__(256) k_node(
        const float* __restrict__ y,
        const int* __restrict__ cursor, const int* __restrict__ bsum,
        const unsigned int* __restrict__ cnts,
        const unsigned int* __restrict__ col,
        const float* __restrict__ b1, const float* __restrict__ W2,
        float* __restrict__ zs, int n) {
    int tid = threadIdx.x;
    int wave = tid >> 6;
    int lane = tid & 63;
    float b1v = b1[lane];
    float w2v = W2[lane];

    int nwaves = gridDim.x * 4;
    int node = blockIdx.x * 4 + wave;
    if (node >= n) return;
    int cu = cursor[node];
    unsigned int cn = cnts[node];

    while (true) {
        int nxt = node + nwaves;
        int cu_nx = 0; unsigned int cn_nx = 0;
        if (nxt < n) { cu_nx = cursor[nxt]; cn_nx = cnts[nxt]; }  // prefetch

        int base = cu + bsum[node >> 8];
        int cnt = (int)(cn & 0xFFFFu);
        float nd = rsqrtf((float)(cn & 0xFFFFu) + 1.0f);   // norm_dst
        float ns = rsqrtf((float)(cn >> 16) + 1.0f);       // norm_src

        float a0 = ns * y[(size_t)node * D + lane];  // self loop
        float a1 = 0.0f, a2 = 0.0f, a3 = 0.0f;

        for (int b0 = 0; b0 < cnt; b0 += 64) {
            int m = cnt - b0; if (m > 64) m = 64;
            unsigned int cw = (lane < m) ? col[base + b0 + lane] : 0u;
            int idx = (int)(cw & 0xFFFFu);
            float w = rsqrtf((float)(cw >> 16) + 1.0f);    // norm_src[idx]
            int j = 0;
            for (; j + 8 <= m; j += 8) {
                int s0 = rl_i(idx, j + 0), s1 = rl_i(idx, j + 1);
                int s2 = rl_i(idx, j + 2), s3 = rl_i(idx, j + 3);
                int s4 = rl_i(idx, j + 4), s5 = rl_i(idx, j + 5);
                int s6 = rl_i(idx, j + 6), s7 = rl_i(idx, j + 7);
                float x0 = y[(size_t)s0 * D + lane];
                float x1 = y[(size_t)s1 * D + lane];
                float x2 = y[(size_t)s2 * D + lane];
                float x3 = y[(size_t)s3 * D + lane];
                float x4 = y[(size_t)s4 * D + lane];
                float x5 = y[(size_t)s5 * D + lane];
                float x6 = y[(size_t)s6 * D + lane];
                float x7 = y[(size_t)s7 * D + lane];
                a0 = fmaf(rl_f(w, j + 0), x0, a0);
                a1 = fmaf(rl_f(w, j + 1), x1, a1);
                a2 = fmaf(rl_f(w, j + 2), x2, a2);
                a3 = fmaf(rl_f(w, j + 3), x3, a3);
                a0 = fmaf(rl_f(w, j + 4), x4, a0);
                a1 = fmaf(rl_f(w, j + 5), x5, a1);
                a2 = fmaf(rl_f(w, j + 6), x6, a2);
                a3 = fmaf(rl_f(w, j + 7), x7, a3);
            }
            for (; j < m; ++j)
                a0 = fmaf(rl_f(w, j), y[(size_t)rl_i(idx, j) * D + lane], a0);
        }

        float h = fmaxf(((a0 + a1) + (a2 + a3)) * nd + b1v, 0.0f);
        float zp = h * w2v;
#pragma unroll
        for (int off = 32; off > 0; off >>= 1) zp += __shfl_down(zp, off);
        if (lane == 0) zs[node] = zp * ns;       // pre-scaled for layer 2

        if (nxt >= n) break;
        node = nxt;
        cu = cu_nx;
        cn = cn_nx;
    }
}

// K6: layer-2 gather, 8 lanes per node
__global__ void k_out(const float* __restrict__ zs,
                      const int* __restrict__ cursor, const int* __restrict__ bsum,
                      const unsigned int* __restrict__ cnts,
                      const unsigned int* __restrict__ col,
                      const float* __restrict__ b2,
                      float* __restrict__ out, int n) {
    int g = blockIdx.x * blockDim.x + threadIdx.x;
    int node = g >> 3;
    int sub = g & 7;
    if (node >= n) return;
    unsigned int cn = cnts[node];
    int base = cursor[node] + bsum[node >> 8];
    int c = (int)(cn & 0xFFFFu);
    float s = (sub == 0) ? zs[node] : 0.0f;   // self loop (zs pre-scaled)
    for (int j = sub; j < c; j += 8) s += zs[col[base + j] & 0xFFFFu];
    s += __shfl_xor(s, 1);
    s += __shfl_xor(s, 2);
    s += __shfl_xor(s, 4);
    if (sub == 0) {
        float nd = rsqrtf((float)(cn & 0xFFFFu) + 1.0f);
        out[node] = nd * s + b2[0];
    }
}

extern "C" void kernel_launch(void* const* d_in, const int* in_sizes, int n_in,
                              void* d_out, int out_size, void* d_ws, size_t ws_size,
                              hipStream_t stream) {
    const float* x  = (const float*)d_in[0];
    const int*   ei = (const int*)d_in[1];
    const float* W1 = (const float*)d_in[2];
    const float* b1 = (const float*)d_in[3];
    const float* W2 = (const float*)d_in[4];
    const float* b2 = (const float*)d_in[5];
    float* out = (float*)d_out;

    const int n = in_sizes[0] / D;   // 50000
    const int e = in_sizes[1] / 2;   // 800000
    const int* src = ei;
    const int* dst = ei + e;

    const int nb = (n + 255) / 256;
    const int ce = (e + NCHUNK - 1) / NCHUNK;               // 12500
    const int W = (n + 1) / 2;                              // 25000 packed words
    const int gblocks = (n + 127) / 128;                    // 391

    // workspace layout -- no overlays
    char* ws = (char*)d_ws;
    int*   cursor = (int*)ws;    ws += sizeof(int) * (size_t)n;
    int*   bsum   = (int*)ws;    ws += sizeof(int) * (size_t)((nb + 255) & ~255);
    unsigned int* cnts = (unsigned int*)ws;  ws += sizeof(unsigned int) * (size_t)n;
    unsigned short* colpref = (unsigned short*)ws;
    ws += sizeof(unsigned short) * (size_t)NCHUNK * n;
    unsigned int* col = (unsigned int*)ws;   ws += sizeof(unsigned int) * (size_t)e;
    unsigned int* part_in = (unsigned int*)ws;
    ws += sizeof(unsigned int) * (size_t)NCHUNK * W;
    unsigned int* part_out = (unsigned int*)ws;
    ws += sizeof(unsigned int) * (size_t)NCHUNK * W;
    float* y  = (float*)ws;      ws += sizeof(float) * (size_t)n * D;
    float* zs = (float*)ws;      ws += sizeof(float) * (size_t)n;

    const int B = 256;
    const size_t smem = (size_t)W * sizeof(unsigned int);   // 100 KB

    k_hist_gemm<<<2 * NCHUNK + gblocks, HTH, smem, stream>>>(
        src, dst, part_in, part_out, e, ce, W, x, W1, y, n);
    k_merge_scan<<<nb, 256, 0, stream>>>(part_in, part_out, colpref, cnts,
                                         cursor, bsum, n, W);
    k_scan_bsum<<<1, 256, 0, stream>>>(bsum, nb);
    k_bin<<<NCHUNK, HTH, smem, stream>>>(src, dst, cursor, bsum, colpref, cnts,
                                         col, e, n, ce, W);
    k_node<<<2048, B, 0, stream>>>(y, cursor, bsum, cnts, col, b1, W2, zs, n);
    k_out<<<((size_t)n * 8 + B - 1) / B, B, 0, stream>>>(zs, cursor, bsum, cnts,
                                                         col, b2, out, n);
}

// Round 16
// 96.792 us; speedup vs baseline: 1.2202x; 1.2202x over previous
//
#include <hip/hip_runtime.h>

// GCN forward, f32. aggregate(x)@W1 == aggregate(x@W1).
// CSR build: single-pass packed-LDS histograms (R15) + tiled 4-pass bin with
// staged global cursors (R14) -- the single-pass bin regressed (7% occupancy).
// Pipeline (6 launches):
//  K1 k_hist_gemm : blocks [0,64)=in-hist (dst), [64,128)=out-hist (src),
//                   [128,..)=gemm y = x @ W1 (8 rows/wave, x via s_load)
//  K2 k_merge_scan: chunk partials -> cnts(in|out<<16) + colpref; block scan
//  K3 k_scan_bsum : exclusive scan of bsum (single block)
//  K4 k_bin_lds   : dim3(64,4); LDS int cur = cursor+bsum+colpref (50KB);
//                   col[p] = src | cnt_out<<16
//  K5 k_node      : per-node gather of y -> +b1, relu, dot W2 -> zs
//  K6 k_out       : layer-2 scalar gather -> out
// fp16-y stays banned (aborted R11/R12).

constexpr int D = 64;
constexpr int NCHUNK = 64;         // edge chunks
constexpr int NODE_TILE = 12800;   // bin tile: 50 KB of int cursors
constexpr int HTH = 1024;          // threads for hist/bin/fused blocks

typedef float f32x8 __attribute__((ext_vector_type(8)));

__device__ __forceinline__ int rl_i(int v, int l) { return __builtin_amdgcn_readlane(v, l); }
__device__ __forceinline__ float rl_f(float v, int l) {
    return __builtin_bit_cast(float, __builtin_amdgcn_readlane(__builtin_bit_cast(int, v), l));
}

// K1: fused hist(in) / hist(out) / gemm, partitioned by blockIdx.x
__global__ void __launch_bounds__(HTH) k_hist_gemm(
        const int* __restrict__ src, const int* __restrict__ dst,
        unsigned int* __restrict__ part_in, unsigned int* __restrict__ part_out,
        int e, int ce, int W,
        const float* __restrict__ x, const float* __restrict__ W1,
        float* __restrict__ y, int n) {
    extern __shared__ unsigned int smem[];
    int tid = threadIdx.x;

    if (blockIdx.x < 2 * NCHUNK) {
        // ---- histogram: packed ushort counters, 2 nodes per uint ----
        unsigned int* h = smem;
        int isOut = (blockIdx.x >= NCHUNK) ? 1 : 0;
        int b = blockIdx.x & (NCHUNK - 1);
        const int* key = isOut ? src : dst;
        for (int i = tid; i < W; i += HTH) h[i] = 0u;
        __syncthreads();
        int lo = b * ce, hi = min(lo + ce, e);
        for (int i = lo + tid; i < hi; i += HTH) {
            int v = key[i];
            atomicAdd(&h[v >> 1], (v & 1) ? 0x10000u : 1u);
        }
        __syncthreads();
        unsigned int* p = (isOut ? part_out : part_in) + (size_t)b * W;
        for (int i = tid; i < W; i += HTH) p[i] = h[i];
    } else {
        // ---- gemm: 16 waves x 8 rows = 128 rows per block ----
        float* sW1 = (float*)smem;
        for (int i = tid; i < D * D; i += HTH) sW1[i] = W1[i];
        __syncthreads();

        int lane = tid & 63;
        int wv = __builtin_amdgcn_readfirstlane(tid >> 6);
        int gb = blockIdx.x - 2 * NCHUNK;
        int r0 = (gb * 16 + wv) * 8;
        if (r0 >= n) return;

        float acc[8];
#pragma unroll
        for (int i = 0; i < 8; ++i) acc[i] = 0.0f;

        if (r0 + 8 <= n) {
            const float* xw = x + (size_t)r0 * D;
#pragma unroll
            for (int kt = 0; kt < 8; ++kt) {
                const float* p = xw + kt * 8;
                f32x8 X0, X1, X2, X3, X4, X5, X6, X7;
                asm volatile(
                    "s_load_dwordx8 %0, %8, 0x0\n\t"
                    "s_load_dwordx8 %1, %8, 0x100\n\t"
                    "s_load_dwordx8 %2, %8, 0x200\n\t"
                    "s_load_dwordx8 %3, %8, 0x300\n\t"
                    "s_load_dwordx8 %4, %8, 0x400\n\t"
                    "s_load_dwordx8 %5, %8, 0x500\n\t"
                    "s_load_dwordx8 %6, %8, 0x600\n\t"
                    "s_load_dwordx8 %7, %8, 0x700\n\t"
                    "s_waitcnt lgkmcnt(0)"
                    : "=s"(X0), "=s"(X1), "=s"(X2), "=s"(X3),
                      "=s"(X4), "=s"(X5), "=s"(X6), "=s"(X7)
                    : "s"(p));
#pragma unroll
                for (int j = 0; j < 8; ++j) {
                    float wk = sW1[(kt * 8 + j) * D + lane];
                    acc[0] = fmaf(X0[j], wk, acc[0]);
                    acc[1] = fmaf(X1[j], wk, acc[1]);
                    acc[2] = fmaf(X2[j], wk, acc[2]);
                    acc[3] = fmaf(X3[j], wk, acc[3]);
                    acc[4] = fmaf(X4[j], wk, acc[4]);
                    acc[5] = fmaf(X5[j], wk, acc[5]);
                    acc[6] = fmaf(X6[j], wk, acc[6]);
                    acc[7] = fmaf(X7[j], wk, acc[7]);
                }
            }
#pragma unroll
            for (int i = 0; i < 8; ++i)
                y[(size_t)(r0 + i) * D + lane] = acc[i];
        } else {
            // tail (never taken for n % 8 == 0)
            float xr[8];
#pragma unroll
            for (int i = 0; i < 8; ++i) {
                int r = r0 + i;
                xr[i] = (r < n) ? x[(size_t)r * D + lane] : 0.0f;
            }
#pragma unroll
            for (int k = 0; k < D; ++k) {
                float wk = sW1[k * D + lane];
#pragma unroll
                for (int i = 0; i < 8; ++i)
                    acc[i] = fmaf(rl_f(xr[i], k), wk, acc[i]);
            }
#pragma unroll
            for (int i = 0; i < 8; ++i) {
                int r = r0 + i;
                if (r < n) y[(size_t)r * D + lane] = acc[i];
            }
        }
    }
}

// K2: per node v, sum chunk partials -> cnts + colpref prefix; block scan of
// cnt_in -> cursor(partial) + bsum
__global__ void k_merge_scan(const unsigned int* __restrict__ part_in,
                             const unsigned int* __restrict__ part_out,
                             unsigned short* __restrict__ colpref,
                             unsigned int* __restrict__ cnts,
                             int* __restrict__ cursor, int* __restrict__ bsum,
                             int n, int W) {
    __shared__ int s[256];
    int tid = threadIdx.x;
    int v = blockIdx.x * 256 + tid;
    int ci = 0;
    if (v < n) {
        int sh = (v & 1) * 16;
        size_t w = (size_t)(v >> 1);
        unsigned int run_in = 0, tout = 0;
        for (int b = 0; b < NCHUNK; ++b) {
            colpref[(size_t)b * n + v] = (unsigned short)run_in;
            run_in += (part_in[(size_t)b * W + w] >> sh) & 0xFFFFu;
            tout   += (part_out[(size_t)b * W + w] >> sh) & 0xFFFFu;
        }
        ci = (int)run_in;
        cnts[v] = run_in | (tout << 16);
    }
    s[tid] = ci;
    __syncthreads();
#pragma unroll
    for (int off = 1; off < 256; off <<= 1) {
        int t = (tid >= off) ? s[tid - off] : 0;
        __syncthreads();
        s[tid] += t;
        __syncthreads();
    }
    if (v < n) cursor[v] = s[tid] - ci;
    if (tid == 255) bsum[blockIdx.x] = s[255];
}

__global__ void k_scan_bsum(int* __restrict__ bsum, int nb) {
    __shared__ int s[256];
    __shared__ int carry;
    int tid = threadIdx.x;
    if (tid == 0) carry = 0;
    __syncthreads();
    for (int start = 0; start < nb; start += 256) {
        int i = start + tid;
        int v = (i < nb) ? bsum[i] : 0;
        s[tid] = v;
        __syncthreads();
#pragma unroll
        for (int off = 1; off < 256; off <<= 1) {
            int t = (tid >= off) ? s[tid - off] : 0;
            __syncthreads();
            s[tid] += t;
            __syncthreads();
        }
        if (i < nb) bsum[i] = s[tid] - v + carry;
        __syncthreads();
        if (tid == 0) carry += s[255];
        __syncthreads();
    }
}

// K4: tiled bin (R14-proven). 64 chunks x 4 node-tiles; LDS holds GLOBAL int
// cursors for the tile; per edge: 1 LDS atomic + cnts[s] L2 load + col store.
__global__ void __launch_bounds__(HTH) k_bin_lds(
        const int* __restrict__ src, const int* __restrict__ dst,
        const int* __restrict__ cursor, const int* __restrict__ bsum,
        const unsigned short* __restrict__ colpref,
        const unsigned int* __restrict__ cnts,
        unsigned int* __restrict__ col, int e, int n, int ce) {
    __shared__ int cur[NODE_TILE];
    int b = blockIdx.x;
    int v0 = blockIdx.y * NODE_TILE;
    int vcnt = min(NODE_TILE, n - v0);
    for (int i = threadIdx.x; i < vcnt; i += HTH) {
        int v = v0 + i;
        cur[i] = cursor[v] + bsum[v >> 8] + (int)colpref[(size_t)b * n + v];
    }
    __syncthreads();
    int lo = b * ce, hi = min(lo + ce, e);
    for (int i = lo + threadIdx.x; i < hi; i += HTH) {
        int d = dst[i];
        unsigned int ud = (unsigned int)(d - v0);
        if (ud < (unsigned int)NODE_TILE) {
            int s = src[i];
            int p = atomicAdd(&cur[ud], 1);
            col[p] = (unsigned int)s | (cnts[s] & 0xFFFF0000u);
        }
    }
}

// K5: one wave per node (grid-stride); all loads coalesced
__global__ void __launch_bounds__(256) k_node(
        const float* __restrict__ y,
        const int* __restrict__ cursor, const int* __restrict__ bsum,
        const unsigned int* __restrict__ cnts,
        const unsigned int* __restrict__ col,
        const float* __restrict__ b1, const float* __restrict__ W2,
        float* __restrict__ zs, int n) {
    int tid = threadIdx.x;
    int wave = tid >> 6;
    int lane = tid & 63;
    float b1v = b1[lane];
    float w2v = W2[lane];

    int nwaves = gridDim.x * 4;
    int node = blockIdx.x * 4 + wave;
    if (node >= n) return;
    int cu = cursor[node];
    unsigned int cn = cnts[node];

    while (true) {
        int nxt = node + nwaves;
        int cu_nx = 0; unsigned int cn_nx = 0;
        if (nxt < n) { cu_nx = cursor[nxt]; cn_nx = cnts[nxt]; }  // prefetch

        int base = cu + bsum[node >> 8];
        int cnt = (int)(cn & 0xFFFFu);
        float nd = rsqrtf((float)(cn & 0xFFFFu) + 1.0f);   // norm_dst
        float ns = rsqrtf((float)(cn >> 16) + 1.0f);       // norm_src

        float a0 = ns * y[(size_t)node * D + lane];  // self loop
        float a1 = 0.0f, a2 = 0.0f, a3 = 0.0f;

        for (int b0 = 0; b0 < cnt; b0 += 64) {
            int m = cnt - b0; if (m > 64) m = 64;
            unsigned int cw = (lane < m) ? col[base + b0 + lane] : 0u;
            int idx = (int)(cw & 0xFFFFu);
            float w = rsqrtf((float)(cw >> 16) + 1.0f);    // norm_src[idx]
            int j = 0;
            for (; j + 8 <= m; j += 8) {
                int s0 = rl_i(idx, j + 0), s1 = rl_i(idx, j + 1);
                int s2 = rl_i(idx, j + 2), s3 = rl_i(idx, j + 3);
                int s4 = rl_i(idx, j + 4), s5 = rl_i(idx, j + 5);
                int s6 = rl_i(idx, j + 6), s7 = rl_i(idx, j + 7);
                float x0 = y[(size_t)s0 * D + lane];
                float x1 = y[(size_t)s1 * D + lane];
                float x2 = y[(size_t)s2 * D + lane];
                float x3 = y[(size_t)s3 * D + lane];
                float x4 = y[(size_t)s4 * D + lane];
                float x5 = y[(size_t)s5 * D + lane];
                float x6 = y[(size_t)s6 * D + lane];
                float x7 = y[(size_t)s7 * D + lane];
                a0 = fmaf(rl_f(w, j + 0), x0, a0);
                a1 = fmaf(rl_f(w, j + 1), x1, a1);
                a2 = fmaf(rl_f(w, j + 2), x2, a2);
                a3 = fmaf(rl_f(w, j + 3), x3, a3);
                a0 = fmaf(rl_f(w, j + 4), x4, a0);
                a1 = fmaf(rl_f(w, j + 5), x5, a1);
                a2 = fmaf(rl_f(w, j + 6), x6, a2);
                a3 = fmaf(rl_f(w, j + 7), x7, a3);
            }
            for (; j < m; ++j)
                a0 = fmaf(rl_f(w, j), y[(size_t)rl_i(idx, j) * D + lane], a0);
        }

        float h = fmaxf(((a0 + a1) + (a2 + a3)) * nd + b1v, 0.0f);
        float zp = h * w2v;
#pragma unroll
        for (int off = 32; off > 0; off >>= 1) zp += __shfl_down(zp, off);
        if (lane == 0) zs[node] = zp * ns;       // pre-scaled for layer 2

        if (nxt >= n) break;
        node = nxt;
        cu = cu_nx;
        cn = cn_nx;
    }
}

// K6: layer-2 gather, 8 lanes per node
__global__ void k_out(const float* __restrict__ zs,
                      const int* __restrict__ cursor, const int* __restrict__ bsum,
                      const unsigned int* __restrict__ cnts,
                      const unsigned int* __restrict__ col,
                      const float* __restrict__ b2,
                      float* __restrict__ out, int n) {
    int g = blockIdx.x * blockDim.x + threadIdx.x;
    int node = g >> 3;
    int sub = g & 7;
    if (node >= n) return;
    unsigned int cn = cnts[node];
    int base = cursor[node] + bsum[node >> 8];
    int c = (int)(cn & 0xFFFFu);
    float s = (sub == 0) ? zs[node] : 0.0f;   // self loop (zs pre-scaled)
    for (int j = sub; j < c; j += 8) s += zs[col[base + j] & 0xFFFFu];
    s += __shfl_xor(s, 1);
    s += __shfl_xor(s, 2);
    s += __shfl_xor(s, 4);
    if (sub == 0) {
        float nd = rsqrtf((float)(cn & 0xFFFFu) + 1.0f);
        out[node] = nd * s + b2[0];
    }
}

extern "C" void kernel_launch(void* const* d_in, const int* in_sizes, int n_in,
                              void* d_out, int out_size, void* d_ws, size_t ws_size,
                              hipStream_t stream) {
    const float* x  = (const float*)d_in[0];
    const int*   ei = (const int*)d_in[1];
    const float* W1 = (const float*)d_in[2];
    const float* b1 = (const float*)d_in[3];
    const float* W2 = (const float*)d_in[4];
    const float* b2 = (const float*)d_in[5];
    float* out = (float*)d_out;

    const int n = in_sizes[0] / D;   // 50000
    const int e = in_sizes[1] / 2;   // 800000
    const int* src = ei;
    const int* dst = ei + e;

    const int nb = (n + 255) / 256;
    const int ce = (e + NCHUNK - 1) / NCHUNK;               // 12500
    const int W = (n + 1) / 2;                              // 25000 packed words
    const int npass = (n + NODE_TILE - 1) / NODE_TILE;      // 4
    const int gblocks = (n + 127) / 128;                    // 391

    // workspace layout -- no overlays
    char* ws = (char*)d_ws;
    int*   cursor = (int*)ws;    ws += sizeof(int) * (size_t)n;
    int*   bsum   = (int*)ws;    ws += sizeof(int) * (size_t)((nb + 255) & ~255);
    unsigned int* cnts = (unsigned int*)ws;  ws += sizeof(unsigned int) * (size_t)n;
    unsigned short* colpref = (unsigned short*)ws;
    ws += sizeof(unsigned short) * (size_t)NCHUNK * n;
    unsigned int* col = (unsigned int*)ws;   ws += sizeof(unsigned int) * (size_t)e;
    unsigned int* part_in = (unsigned int*)ws;
    ws += sizeof(unsigned int) * (size_t)NCHUNK * W;
    unsigned int* part_out = (unsigned int*)ws;
    ws += sizeof(unsigned int) * (size_t)NCHUNK * W;
    float* y  = (float*)ws;      ws += sizeof(float) * (size_t)n * D;
    float* zs = (float*)ws;      ws += sizeof(float) * (size_t)n;

    const int B = 256;
    const size_t smem = (size_t)W * sizeof(unsigned int);   // 100 KB (hist blocks)

    k_hist_gemm<<<2 * NCHUNK + gblocks, HTH, smem, stream>>>(
        src, dst, part_in, part_out, e, ce, W, x, W1, y, n);
    k_merge_scan<<<nb, 256, 0, stream>>>(part_in, part_out, colpref, cnts,
                                         cursor, bsum, n, W);
    k_scan_bsum<<<1, 256, 0, stream>>>(bsum, nb);
    k_bin_lds<<<dim3(NCHUNK, npass), HTH, 0, stream>>>(
        src, dst, cursor, bsum, colpref, cnts, col, e, n, ce);
    k_node<<<2048, B, 0, stream>>>(y, cursor, bsum, cnts, col, b1, W2, zs, n);
    k_out<<<((size_t)n * 8 + B - 1) / B, B, 0, stream>>>(zs, cursor, bsum, cnts,
                                                         col, b2, out, n);
}

// Round 19
// 96.388 us; speedup vs baseline: 1.2253x; 1.0042x over previous
//
#include <hip/hip_runtime.h>

// GCN forward, f32. aggregate(x)@W1 == aggregate(x@W1).
// CSR build: single-pass packed-LDS hists + tiled bin (R16-proven, 96.8us).
// R17/R18's float4 k_node produced a deterministic absmax 2.8e-2 across two
// configurations -> reverted wholesale to the R16-proven scalar k_node.
// Pipeline (6 launches):
//  K1 k_hist_gemm : blocks [0,64)=in-hist (dst), [64,128)=out-hist (src),
//                   [128,..)=gemm y = x @ W1 (8 rows/wave, x via s_load)
//  K2 k_merge_scan: chunk partials -> cnts + colpref; block scan -> cursor,bsum
//  K3 k_scan_bsum : exclusive scan of bsum (single block)
//  K4 k_bin_lds   : dim3(64,4); LDS int cur = cursor+bsum+colpref (50KB)
//  K5 k_node      : per-node gather of y -> +b1, relu, dot W2 -> zs
//  K6 k_out       : layer-2 scalar gather -> out
// fp16-y stays banned (aborted R11/R12); float4-gather k_node banned (R17/R18).

constexpr int D = 64;
constexpr int NCHUNK = 64;         // edge chunks
constexpr int NODE_TILE = 12800;   // bin tile: 50 KB of int cursors
constexpr int HTH = 1024;          // threads for hist/bin/fused blocks

typedef float f32x8 __attribute__((ext_vector_type(8)));

__device__ __forceinline__ int rl_i(int v, int l) { return __builtin_amdgcn_readlane(v, l); }
__device__ __forceinline__ float rl_f(float v, int l) {
    return __builtin_bit_cast(float, __builtin_amdgcn_readlane(__builtin_bit_cast(int, v), l));
}

// K1: fused hist(in) / hist(out) / gemm, partitioned by blockIdx.x
__global__ void __launch_bounds__(HTH) k_hist_gemm(
        const int* __restrict__ src, const int* __restrict__ dst,
        unsigned int* __restrict__ part_in, unsigned int* __restrict__ part_out,
        int e, int ce, int W,
        const float* __restrict__ x, const float* __restrict__ W1,
        float* __restrict__ y, int n) {
    extern __shared__ unsigned int smem[];
    int tid = threadIdx.x;

    if (blockIdx.x < 2 * NCHUNK) {
        // ---- histogram: packed ushort counters, 2 nodes per uint ----
        unsigned int* h = smem;
        int isOut = (blockIdx.x >= NCHUNK) ? 1 : 0;
        int b = blockIdx.x & (NCHUNK - 1);
        const int* key = isOut ? src : dst;
        for (int i = tid; i < W; i += HTH) h[i] = 0u;
        __syncthreads();
        int lo = b * ce, hi = min(lo + ce, e);
        for (int i = lo + tid; i < hi; i += HTH) {
            int v = key[i];
            atomicAdd(&h[v >> 1], (v & 1) ? 0x10000u : 1u);
        }
        __syncthreads();
        unsigned int* p = (isOut ? part_out : part_in) + (size_t)b * W;
        for (int i = tid; i < W; i += HTH) p[i] = h[i];
    } else {
        // ---- gemm: 16 waves x 8 rows = 128 rows per block ----
        float* sW1 = (float*)smem;
        for (int i = tid; i < D * D; i += HTH) sW1[i] = W1[i];
        __syncthreads();

        int lane = tid & 63;
        int wv = __builtin_amdgcn_readfirstlane(tid >> 6);
        int gb = blockIdx.x - 2 * NCHUNK;
        int r0 = (gb * 16 + wv) * 8;
        if (r0 >= n) return;

        float acc[8];
#pragma unroll
        for (int i = 0; i < 8; ++i) acc[i] = 0.0f;

        if (r0 + 8 <= n) {
            const float* xw = x + (size_t)r0 * D;
#pragma unroll
            for (int kt = 0; kt < 8; ++kt) {
                const float* p = xw + kt * 8;
                f32x8 X0, X1, X2, X3, X4, X5, X6, X7;
                asm volatile(
                    "s_load_dwordx8 %0, %8, 0x0\n\t"
                    "s_load_dwordx8 %1, %8, 0x100\n\t"
                    "s_load_dwordx8 %2, %8, 0x200\n\t"
                    "s_load_dwordx8 %3, %8, 0x300\n\t"
                    "s_load_dwordx8 %4, %8, 0x400\n\t"
                    "s_load_dwordx8 %5, %8, 0x500\n\t"
                    "s_load_dwordx8 %6, %8, 0x600\n\t"
                    "s_load_dwordx8 %7, %8, 0x700\n\t"
                    "s_waitcnt lgkmcnt(0)"
                    : "=s"(X0), "=s"(X1), "=s"(X2), "=s"(X3),
                      "=s"(X4), "=s"(X5), "=s"(X6), "=s"(X7)
                    : "s"(p));
#pragma unroll
                for (int j = 0; j < 8; ++j) {
                    float wk = sW1[(kt * 8 + j) * D + lane];
                    acc[0] = fmaf(X0[j], wk, acc[0]);
                    acc[1] = fmaf(X1[j], wk, acc[1]);
                    acc[2] = fmaf(X2[j], wk, acc[2]);
                    acc[3] = fmaf(X3[j], wk, acc[3]);
                    acc[4] = fmaf(X4[j], wk, acc[4]);
                    acc[5] = fmaf(X5[j], wk, acc[5]);
                    acc[6] = fmaf(X6[j], wk, acc[6]);
                    acc[7] = fmaf(X7[j], wk, acc[7]);
                }
            }
#pragma unroll
            for (int i = 0; i < 8; ++i)
                y[(size_t)(r0 + i) * D + lane] = acc[i];
        } else {
            // tail (never taken for n % 8 == 0)
            float xr[8];
#pragma unroll
            for (int i = 0; i < 8; ++i) {
                int r = r0 + i;
                xr[i] = (r < n) ? x[(size_t)r * D + lane] : 0.0f;
            }
#pragma unroll
            for (int k = 0; k < D; ++k) {
                float wk = sW1[k * D + lane];
#pragma unroll
                for (int i = 0; i < 8; ++i)
                    acc[i] = fmaf(rl_f(xr[i], k), wk, acc[i]);
            }
#pragma unroll
            for (int i = 0; i < 8; ++i) {
                int r = r0 + i;
                if (r < n) y[(size_t)r * D + lane] = acc[i];
            }
        }
    }
}

// K2: per node v, sum chunk partials -> cnts + colpref; block scan of cnt_in
// -> cursor(partial) + bsum
__global__ void k_merge_scan(const unsigned int* __restrict__ part_in,
                             const unsigned int* __restrict__ part_out,
                             unsigned short* __restrict__ colpref,
                             unsigned int* __restrict__ cnts,
                             int* __restrict__ cursor, int* __restrict__ bsum,
                             int n, int W) {
    __shared__ int s[256];
    int tid = threadIdx.x;
    int v = blockIdx.x * 256 + tid;
    int ci = 0;
    if (v < n) {
        int sh = (v & 1) * 16;
        size_t w = (size_t)(v >> 1);
        unsigned int run_in = 0, tout = 0;
        for (int b = 0; b < NCHUNK; ++b) {
            colpref[(size_t)b * n + v] = (unsigned short)run_in;
            run_in += (part_in[(size_t)b * W + w] >> sh) & 0xFFFFu;
            tout   += (part_out[(size_t)b * W + w] >> sh) & 0xFFFFu;
        }
        ci = (int)run_in;
        cnts[v] = run_in | (tout << 16);
    }
    s[tid] = ci;
    __syncthreads();
#pragma unroll
    for (int off = 1; off < 256; off <<= 1) {
        int t = (tid >= off) ? s[tid - off] : 0;
        __syncthreads();
        s[tid] += t;
        __syncthreads();
    }
    if (v < n) cursor[v] = s[tid] - ci;
    if (tid == 255) bsum[blockIdx.x] = s[255];
}

__global__ void k_scan_bsum(int* __restrict__ bsum, int nb) {
    __shared__ int s[256];
    __shared__ int carry;
    int tid = threadIdx.x;
    if (tid == 0) carry = 0;
    __syncthreads();
    for (int start = 0; start < nb; start += 256) {
        int i = start + tid;
        int v = (i < nb) ? bsum[i] : 0;
        s[tid] = v;
        __syncthreads();
#pragma unroll
        for (int off = 1; off < 256; off <<= 1) {
            int t = (tid >= off) ? s[tid - off] : 0;
            __syncthreads();
            s[tid] += t;
            __syncthreads();
        }
        if (i < nb) bsum[i] = s[tid] - v + carry;
        __syncthreads();
        if (tid == 0) carry += s[255];
        __syncthreads();
    }
}

// K4: tiled bin (R14/R16-proven). 64 chunks x 4 node-tiles; LDS = global int
// cursors for the tile; per edge: 1 LDS atomic + cnts[s] L2 load + col store.
__global__ void __launch_bounds__(HTH) k_bin_lds(
        const int* __restrict__ src, const int* __restrict__ dst,
        const int* __restrict__ cursor, const int* __restrict__ bsum,
        const unsigned short* __restrict__ colpref,
        const unsigned int* __restrict__ cnts,
        unsigned int* __restrict__ col, int e, int n, int ce) {
    __shared__ int cur[NODE_TILE];
    int b = blockIdx.x;
    int v0 = blockIdx.y * NODE_TILE;
    int vcnt = min(NODE_TILE, n - v0);
    for (int i = threadIdx.x; i < vcnt; i += HTH) {
        int v = v0 + i;
        cur[i] = cursor[v] + bsum[v >> 8] + (int)colpref[(size_t)b * n + v];
    }
    __syncthreads();
    int lo = b * ce, hi = min(lo + ce, e);
    for (int i = lo + threadIdx.x; i < hi; i += HTH) {
        int d = dst[i];
        unsigned int ud = (unsigned int)(d - v0);
        if (ud < (unsigned int)NODE_TILE) {
            int s = src[i];
            int p = atomicAdd(&cur[ud], 1);
            col[p] = (unsigned int)s | (cnts[s] & 0xFFFF0000u);
        }
    }
}

// K5: one wave per node (grid-stride); all loads coalesced (R16-proven)
__global__ void __launch_bounds__(256) k_node(
        const float* __restrict__ y,
        const int* __restrict__ cursor, const int* __restrict__ bsum,
        const unsigned int* __restrict__ cnts,
        const unsigned int* __restrict__ col,
        const float* __restrict__ b1, const float* __restrict__ W2,
        float* __restrict__ zs, int n) {
    int tid = threadIdx.x;
    int wave = tid >> 6;
    int lane = tid & 63;
    float b1v = b1[lane];
    float w2v = W2[lane];

    int nwaves = gridDim.x * 4;
    int node = blockIdx.x * 4 + wave;
    if (node >= n) return;
    int cu = cursor[node];
    unsigned int cn = cnts[node];

    while (true) {
        int nxt = node + nwaves;
        int cu_nx = 0; unsigned int cn_nx = 0;
        if (nxt < n) { cu_nx = cursor[nxt]; cn_nx = cnts[nxt]; }  // prefetch

        int base = cu + bsum[node >> 8];
        int cnt = (int)(cn & 0xFFFFu);
        float nd = rsqrtf((float)(cn & 0xFFFFu) + 1.0f);   // norm_dst
        float ns = rsqrtf((float)(cn >> 16) + 1.0f);       // norm_src

        float a0 = ns * y[(size_t)node * D + lane];  // self loop
        float a1 = 0.0f, a2 = 0.0f, a3 = 0.0f;

        for (int b0 = 0; b0 < cnt; b0 += 64) {
            int m = cnt - b0; if (m > 64) m = 64;
            unsigned int cw = (lane < m) ? col[base + b0 + lane] : 0u;
            int idx = (int)(cw & 0xFFFFu);
            float w = rsqrtf((float)(cw >> 16) + 1.0f);    // norm_src[idx]
            int j = 0;
            for (; j + 8 <= m; j += 8) {
                int s0 = rl_i(idx, j + 0), s1 = rl_i(idx, j + 1);
                int s2 = rl_i(idx, j + 2), s3 = rl_i(idx, j + 3);
                int s4 = rl_i(idx, j + 4), s5 = rl_i(idx, j + 5);
                int s6 = rl_i(idx, j + 6), s7 = rl_i(idx, j + 7);
                float x0 = y[(size_t)s0 * D + lane];
                float x1 = y[(size_t)s1 * D + lane];
                float x2 = y[(size_t)s2 * D + lane];
                float x3 = y[(size_t)s3 * D + lane];
                float x4 = y[(size_t)s4 * D + lane];
                float x5 = y[(size_t)s5 * D + lane];
                float x6 = y[(size_t)s6 * D + lane];
                float x7 = y[(size_t)s7 * D + lane];
                a0 = fmaf(rl_f(w, j + 0), x0, a0);
                a1 = fmaf(rl_f(w, j + 1), x1, a1);
                a2 = fmaf(rl_f(w, j + 2), x2, a2);
                a3 = fmaf(rl_f(w, j + 3), x3, a3);
                a0 = fmaf(rl_f(w, j + 4), x4, a0);
                a1 = fmaf(rl_f(w, j + 5), x5, a1);
                a2 = fmaf(rl_f(w, j + 6), x6, a2);
                a3 = fmaf(rl_f(w, j + 7), x7, a3);
            }
            for (; j < m; ++j)
                a0 = fmaf(rl_f(w, j), y[(size_t)rl_i(idx, j) * D + lane], a0);
        }

        float h = fmaxf(((a0 + a1) + (a2 + a3)) * nd + b1v, 0.0f);
        float zp = h * w2v;
#pragma unroll
        for (int off = 32; off > 0; off >>= 1) zp += __shfl_down(zp, off);
        if (lane == 0) zs[node] = zp * ns;       // pre-scaled for layer 2

        if (nxt >= n) break;
        node = nxt;
        cu = cu_nx;
        cn = cn_nx;
    }
}

// K6: layer-2 gather, 8 lanes per node
__global__ void k_out(const float* __restrict__ zs,
                      const int* __restrict__ cursor, const int* __restrict__ bsum,
                      const unsigned int* __restrict__ cnts,
                      const unsigned int* __restrict__ col,
                      const float* __restrict__ b2,
                      float* __restrict__ out, int n) {
    int g = blockIdx.x * blockDim.x + threadIdx.x;
    int node = g >> 3;
    int sub = g & 7;
    if (node >= n) return;
    unsigned int cn = cnts[node];
    int base = cursor[node] + bsum[node >> 8];
    int c = (int)(cn & 0xFFFFu);
    float s = (sub == 0) ? zs[node] : 0.0f;   // self loop (zs pre-scaled)
    for (int j = sub; j < c; j += 8) s += zs[col[base + j] & 0xFFFFu];
    s += __shfl_xor(s, 1);
    s += __shfl_xor(s, 2);
    s += __shfl_xor(s, 4);
    if (sub == 0) {
        float nd = rsqrtf((float)(cn & 0xFFFFu) + 1.0f);
        out[node] = nd * s + b2[0];
    }
}

extern "C" void kernel_launch(void* const* d_in, const int* in_sizes, int n_in,
                              void* d_out, int out_size, void* d_ws, size_t ws_size,
                              hipStream_t stream) {
    const float* x  = (const float*)d_in[0];
    const int*   ei = (const int*)d_in[1];
    const float* W1 = (const float*)d_in[2];
    const float* b1 = (const float*)d_in[3];
    const float* W2 = (const float*)d_in[4];
    const float* b2 = (const float*)d_in[5];
    float* out = (float*)d_out;

    const int n = in_sizes[0] / D;   // 50000
    const int e = in_sizes[1] / 2;   // 800000
    const int* src = ei;
    const int* dst = ei + e;

    const int nb = (n + 255) / 256;
    const int ce = (e + NCHUNK - 1) / NCHUNK;               // 12500
    const int W = (n + 1) / 2;                              // 25000 packed words
    const int npass = (n + NODE_TILE - 1) / NODE_TILE;      // 4
    const int gblocks = (n + 127) / 128;                    // 391

    // workspace layout -- no overlays
    char* ws = (char*)d_ws;
    int*   cursor = (int*)ws;    ws += sizeof(int) * (size_t)n;
    int*   bsum   = (int*)ws;    ws += sizeof(int) * (size_t)((nb + 255) & ~255);
    unsigned int* cnts = (unsigned int*)ws;  ws += sizeof(unsigned int) * (size_t)n;
    unsigned short* colpref = (unsigned short*)ws;
    ws += sizeof(unsigned short) * (size_t)NCHUNK * n;
    unsigned int* col = (unsigned int*)ws;   ws += sizeof(unsigned int) * (size_t)e;
    unsigned int* part_in = (unsigned int*)ws;
    ws += sizeof(unsigned int) * (size_t)NCHUNK * W;
    unsigned int* part_out = (unsigned int*)ws;
    ws += sizeof(unsigned int) * (size_t)NCHUNK * W;
    float* y  = (float*)ws;      ws += sizeof(float) * (size_t)n * D;
    float* zs = (float*)ws;      ws += sizeof(float) * (size_t)n;

    const int B = 256;
    const size_t smem = (size_t)W * sizeof(unsigned int);   // 100 KB (hist blocks)

    k_hist_gemm<<<2 * NCHUNK + gblocks, HTH, smem, stream>>>(
        src, dst, part_in, part_out, e, ce, W, x, W1, y, n);
    k_merge_scan<<<nb, 256, 0, stream>>>(part_in, part_out, colpref, cnts,
                                         cursor, bsum, n, W);
    k_scan_bsum<<<1, 256, 0, stream>>>(bsum, nb);
    k_bin_lds<<<dim3(NCHUNK, npass), HTH, 0, stream>>>(
        src, dst, cursor, bsum, colpref, cnts, col, e, n, ce);
    k_node<<<2048, B, 0, stream>>>(y, cursor, bsum, cnts, col, b1, W2, zs, n);
    k_out<<<((size_t)n * 8 + B - 1) / B, B, 0, stream>>>(zs, cursor, bsum, cnts,
                                                         col, b2, out, n);
}

// Round 20
// 94.203 us; speedup vs baseline: 1.2537x; 1.0232x over previous
//
#include <hip/hip_runtime.h>

// GCN forward, f32. aggregate(x)@W1 == aggregate(x@W1).
// CSR build: single-pass packed-LDS hists + tiled bin (R16-proven).
// k_node: float4 gather, FIXED tail -- R17/R18's bug was a convergent __shfl
// inside a divergent ternary (ds_bpermute from masked-off lanes is undefined);
// now both shfls execute unconditionally and w0 is zeroed by select after.
// Pipeline (6 launches):
//  K1 k_hist_gemm : blocks [0,64)=in-hist (dst), [64,128)=out-hist (src),
//                   [128,..)=gemm y = x @ W1 (8 rows/wave, x via s_load)
//  K2 k_merge_scan: chunk partials -> cnts + colpref; block scan -> cursor,bsum
//  K3 k_scan_bsum : exclusive scan of bsum (single block)
//  K4 k_bin_lds   : dim3(64,4); LDS int cur = cursor+bsum+colpref (50KB)
//  K5 k_node      : per-node float4 gather of y -> +b1, relu, dot W2 -> zs
//  K6 k_out       : layer-2 scalar gather -> out
// fp16-y stays banned (aborted R11/R12).

constexpr int D = 64;
constexpr int NCHUNK = 64;         // edge chunks
constexpr int NODE_TILE = 12800;   // bin tile: 50 KB of int cursors
constexpr int HTH = 1024;          // threads for hist/bin/fused blocks

typedef float f32x8 __attribute__((ext_vector_type(8)));

__device__ __forceinline__ int rl_i(int v, int l) { return __builtin_amdgcn_readlane(v, l); }
__device__ __forceinline__ float rl_f(float v, int l) {
    return __builtin_bit_cast(float, __builtin_amdgcn_readlane(__builtin_bit_cast(int, v), l));
}

// K1: fused hist(in) / hist(out) / gemm, partitioned by blockIdx.x
__global__ void __launch_bounds__(HTH) k_hist_gemm(
        const int* __restrict__ src, const int* __restrict__ dst,
        unsigned int* __restrict__ part_in, unsigned int* __restrict__ part_out,
        int e, int ce, int W,
        const float* __restrict__ x, const float* __restrict__ W1,
        float* __restrict__ y, int n) {
    extern __shared__ unsigned int smem[];
    int tid = threadIdx.x;

    if (blockIdx.x < 2 * NCHUNK) {
        // ---- histogram: packed ushort counters, 2 nodes per uint ----
        unsigned int* h = smem;
        int isOut = (blockIdx.x >= NCHUNK) ? 1 : 0;
        int b = blockIdx.x & (NCHUNK - 1);
        const int* key = isOut ? src : dst;
        for (int i = tid; i < W; i += HTH) h[i] = 0u;
        __syncthreads();
        int lo = b * ce, hi = min(lo + ce, e);
        for (int i = lo + tid; i < hi; i += HTH) {
            int v = key[i];
            atomicAdd(&h[v >> 1], (v & 1) ? 0x10000u : 1u);
        }
        __syncthreads();
        unsigned int* p = (isOut ? part_out : part_in) + (size_t)b * W;
        for (int i = tid; i < W; i += HTH) p[i] = h[i];
    } else {
        // ---- gemm: 16 waves x 8 rows = 128 rows per block ----
        float* sW1 = (float*)smem;
        for (int i = tid; i < D * D; i += HTH) sW1[i] = W1[i];
        __syncthreads();

        int lane = tid & 63;
        int wv = __builtin_amdgcn_readfirstlane(tid >> 6);
        int gb = blockIdx.x - 2 * NCHUNK;
        int r0 = (gb * 16 + wv) * 8;
        if (r0 >= n) return;

        float acc[8];
#pragma unroll
        for (int i = 0; i < 8; ++i) acc[i] = 0.0f;

        if (r0 + 8 <= n) {
            const float* xw = x + (size_t)r0 * D;
#pragma unroll
            for (int kt = 0; kt < 8; ++kt) {
                const float* p = xw + kt * 8;
                f32x8 X0, X1, X2, X3, X4, X5, X6, X7;
                asm volatile(
                    "s_load_dwordx8 %0, %8, 0x0\n\t"
                    "s_load_dwordx8 %1, %8, 0x100\n\t"
                    "s_load_dwordx8 %2, %8, 0x200\n\t"
                    "s_load_dwordx8 %3, %8, 0x300\n\t"
                    "s_load_dwordx8 %4, %8, 0x400\n\t"
                    "s_load_dwordx8 %5, %8, 0x500\n\t"
                    "s_load_dwordx8 %6, %8, 0x600\n\t"
                    "s_load_dwordx8 %7, %8, 0x700\n\t"
                    "s_waitcnt lgkmcnt(0)"
                    : "=s"(X0), "=s"(X1), "=s"(X2), "=s"(X3),
                      "=s"(X4), "=s"(X5), "=s"(X6), "=s"(X7)
                    : "s"(p));
#pragma unroll
                for (int j = 0; j < 8; ++j) {
                    float wk = sW1[(kt * 8 + j) * D + lane];
                    acc[0] = fmaf(X0[j], wk, acc[0]);
                    acc[1] = fmaf(X1[j], wk, acc[1]);
                    acc[2] = fmaf(X2[j], wk, acc[2]);
                    acc[3] = fmaf(X3[j], wk, acc[3]);
                    acc[4] = fmaf(X4[j], wk, acc[4]);
                    acc[5] = fmaf(X5[j], wk, acc[5]);
                    acc[6] = fmaf(X6[j], wk, acc[6]);
                    acc[7] = fmaf(X7[j], wk, acc[7]);
                }
            }
#pragma unroll
            for (int i = 0; i < 8; ++i)
                y[(size_t)(r0 + i) * D + lane] = acc[i];
        } else {
            // tail (never taken for n % 8 == 0)
            float xr[8];
#pragma unroll
            for (int i = 0; i < 8; ++i) {
                int r = r0 + i;
                xr[i] = (r < n) ? x[(size_t)r * D + lane] : 0.0f;
            }
#pragma unroll
            for (int k = 0; k < D; ++k) {
                float wk = sW1[k * D + lane];
#pragma unroll
                for (int i = 0; i < 8; ++i)
                    acc[i] = fmaf(rl_f(xr[i], k), wk, acc[i]);
            }
#pragma unroll
            for (int i = 0; i < 8; ++i) {
                int r = r0 + i;
                if (r < n) y[(size_t)r * D + lane] = acc[i];
            }
        }
    }
}

// K2: per node v, sum chunk partials -> cnts + colpref; block scan of cnt_in
// -> cursor(partial) + bsum
__global__ void k_merge_scan(const unsigned int* __restrict__ part_in,
                             const unsigned int* __restrict__ part_out,
                             unsigned short* __restrict__ colpref,
                             unsigned int* __restrict__ cnts,
                             int* __restrict__ cursor, int* __restrict__ bsum,
                             int n, int W) {
    __shared__ int s[256];
    int tid = threadIdx.x;
    int v = blockIdx.x * 256 + tid;
    int ci = 0;
    if (v < n) {
        int sh = (v & 1) * 16;
        size_t w = (size_t)(v >> 1);
        unsigned int run_in = 0, tout = 0;
        for (int b = 0; b < NCHUNK; ++b) {
            colpref[(size_t)b * n + v] = (unsigned short)run_in;
            run_in += (part_in[(size_t)b * W + w] >> sh) & 0xFFFFu;
            tout   += (part_out[(size_t)b * W + w] >> sh) & 0xFFFFu;
        }
        ci = (int)run_in;
        cnts[v] = run_in | (tout << 16);
    }
    s[tid] = ci;
    __syncthreads();
#pragma unroll
    for (int off = 1; off < 256; off <<= 1) {
        int t = (tid >= off) ? s[tid - off] : 0;
        __syncthreads();
        s[tid] += t;
        __syncthreads();
    }
    if (v < n) cursor[v] = s[tid] - ci;
    if (tid == 255) bsum[blockIdx.x] = s[255];
}

__global__ void k_scan_bsum(int* __restrict__ bsum, int nb) {
    __shared__ int s[256];
    __shared__ int carry;
    int tid = threadIdx.x;
    if (tid == 0) carry = 0;
    __syncthreads();
    for (int start = 0; start < nb; start += 256) {
        int i = start + tid;
        int v = (i < nb) ? bsum[i] : 0;
        s[tid] = v;
        __syncthreads();
#pragma unroll
        for (int off = 1; off < 256; off <<= 1) {
            int t = (tid >= off) ? s[tid - off] : 0;
            __syncthreads();
            s[tid] += t;
            __syncthreads();
        }
        if (i < nb) bsum[i] = s[tid] - v + carry;
        __syncthreads();
        if (tid == 0) carry += s[255];
        __syncthreads();
    }
}

// K4: tiled bin (R14/R16-proven). 64 chunks x 4 node-tiles; LDS = global int
// cursors for the tile; per edge: 1 LDS atomic + cnts[s] L2 load + col store.
__global__ void __launch_bounds__(HTH) k_bin_lds(
        const int* __restrict__ src, const int* __restrict__ dst,
        const int* __restrict__ cursor, const int* __restrict__ bsum,
        const unsigned short* __restrict__ colpref,
        const unsigned int* __restrict__ cnts,
        unsigned int* __restrict__ col, int e, int n, int ce) {
    __shared__ int cur[NODE_TILE];
    int b = blockIdx.x;
    int v0 = blockIdx.y * NODE_TILE;
    int vcnt = min(NODE_TILE, n - v0);
    for (int i = threadIdx.x; i < vcnt; i += HTH) {
        int v = v0 + i;
        cur[i] = cursor[v] + bsum[v >> 8] + (int)colpref[(size_t)b * n + v];
    }
    __syncthreads();
    int lo = b * ce, hi = min(lo + ce, e);
    for (int i = lo + threadIdx.x; i < hi; i += HTH) {
        int d = dst[i];
        unsigned int ud = (unsigned int)(d - v0);
        if (ud < (unsigned int)NODE_TILE) {
            int s = src[i];
            int p = atomicAdd(&cur[ud], 1);
            col[p] = (unsigned int)s | (cnts[s] & 0xFFFF0000u);
        }
    }
}

// K5: one wave per node; float4 gather -- lane l owns columns 4*(l&15)..+3,
// subgroup l>>4 handles every 4th edge; one dwordx4 load covers 4 edges.
// All __shfl executed UNCONDITIONALLY (divergent-shfl bug fixed).
__global__ void __launch_bounds__(256) k_node(
        const float* __restrict__ y,
        const int* __restrict__ cursor, const int* __restrict__ bsum,
        const unsigned int* __restrict__ cnts,
        const unsigned int* __restrict__ col,
        const float* __restrict__ b1, const float* __restrict__ W2,
        float* __restrict__ zs, int n) {
    int tid = threadIdx.x;
    int wave = tid >> 6;
    int lane = tid & 63;
    int sub = lane >> 4;          // 0..3
    int c4 = (lane & 15) * 4;     // column group
    float4 b14 = *(const float4*)&b1[c4];
    float4 w24 = *(const float4*)&W2[c4];

    int nwaves = gridDim.x * 4;
    int node = blockIdx.x * 4 + wave;
    if (node >= n) return;
    int cu = cursor[node];
    unsigned int cn = cnts[node];

    while (true) {
        int nxt = node + nwaves;
        int cu_nx = 0; unsigned int cn_nx = 0;
        if (nxt < n) { cu_nx = cursor[nxt]; cn_nx = cnts[nxt]; }  // prefetch

        int base = cu + bsum[node >> 8];
        int cnt = (int)(cn & 0xFFFFu);
        float nd = rsqrtf((float)(cn & 0xFFFFu) + 1.0f);   // norm_dst
        float ns = rsqrtf((float)(cn >> 16) + 1.0f);       // norm_src

        float4 a0 = make_float4(0.f, 0.f, 0.f, 0.f);
        float4 a1 = make_float4(0.f, 0.f, 0.f, 0.f);

        for (int b0 = 0; b0 < cnt; b0 += 64) {
            int m = cnt - b0; if (m > 64) m = 64;
            unsigned int cw = (lane < m) ? col[base + b0 + lane] : 0u;
            int idx = (int)(cw & 0xFFFFu);
            float nsw = rsqrtf((float)(cw >> 16) + 1.0f);
            int j = 0;
            for (; j + 8 <= m; j += 8) {
                // all lanes active; sources j0,j1 < m always
                int j0 = j + sub, j1 = j + 4 + sub;
                int s0 = __shfl(idx, j0);
                int s1 = __shfl(idx, j1);
                float w0 = __shfl(nsw, j0);
                float w1 = __shfl(nsw, j1);
                float4 r0 = *(const float4*)&y[(size_t)s0 * D + c4];
                float4 r1 = *(const float4*)&y[(size_t)s1 * D + c4];
                a0.x = fmaf(w0, r0.x, a0.x); a0.y = fmaf(w0, r0.y, a0.y);
                a0.z = fmaf(w0, r0.z, a0.z); a0.w = fmaf(w0, r0.w, a0.w);
                a1.x = fmaf(w1, r1.x, a1.x); a1.y = fmaf(w1, r1.y, a1.y);
                a1.z = fmaf(w1, r1.z, a1.z); a1.w = fmaf(w1, r1.w, a1.w);
            }
            for (; j < m; j += 4) {
                int je = j + sub;
                int jj = (je < m) ? je : (m - 1);   // jj < m always
                // UNCONDITIONAL shfls (fix): every lane participates, then
                // out-of-range subgroups zero their weight by select.
                int s0 = __shfl(idx, jj);
                float w0s = __shfl(nsw, jj);
                float w0 = (je < m) ? w0s : 0.0f;
                float4 r0 = *(const float4*)&y[(size_t)s0 * D + c4];
                a0.x = fmaf(w0, r0.x, a0.x); a0.y = fmaf(w0, r0.y, a0.y);
                a0.z = fmaf(w0, r0.z, a0.z); a0.w = fmaf(w0, r0.w, a0.w);
            }
        }
        a0.x += a1.x; a0.y += a1.y; a0.z += a1.z; a0.w += a1.w;
        // reduce the 4 subgroups (lanes l, l^16, l^32, l^48)
        a0.x += __shfl_xor(a0.x, 16); a0.y += __shfl_xor(a0.y, 16);
        a0.z += __shfl_xor(a0.z, 16); a0.w += __shfl_xor(a0.w, 16);
        a0.x += __shfl_xor(a0.x, 32); a0.y += __shfl_xor(a0.y, 32);
        a0.z += __shfl_xor(a0.z, 32); a0.w += __shfl_xor(a0.w, 32);
        // self loop (added once per lane after reduction; copies consistent)
        float4 ys = *(const float4*)&y[(size_t)node * D + c4];
        a0.x = fmaf(ns, ys.x, a0.x); a0.y = fmaf(ns, ys.y, a0.y);
        a0.z = fmaf(ns, ys.z, a0.z); a0.w = fmaf(ns, ys.w, a0.w);

        float4 h;
        h.x = fmaxf(fmaf(a0.x, nd, b14.x), 0.0f);
        h.y = fmaxf(fmaf(a0.y, nd, b14.y), 0.0f);
        h.z = fmaxf(fmaf(a0.z, nd, b14.z), 0.0f);
        h.w = fmaxf(fmaf(a0.w, nd, b14.w), 0.0f);
        float zp = h.x * w24.x + h.y * w24.y + h.z * w24.z + h.w * w24.w;
        zp += __shfl_xor(zp, 1);
        zp += __shfl_xor(zp, 2);
        zp += __shfl_xor(zp, 4);
        zp += __shfl_xor(zp, 8);
        if (lane == 0) zs[node] = zp * ns;       // pre-scaled for layer 2

        if (nxt >= n) break;
        node = nxt;
        cu = cu_nx;
        cn = cn_nx;
    }
}

// K6: layer-2 gather, 8 lanes per node
__global__ void k_out(const float* __restrict__ zs,
                      const int* __restrict__ cursor, const int* __restrict__ bsum,
                      const unsigned int* __restrict__ cnts,
                      const unsigned int* __restrict__ col,
                      const float* __restrict__ b2,
                      float* __restrict__ out, int n) {
    int g = blockIdx.x * blockDim.x + threadIdx.x;
    int node = g >> 3;
    int sub = g & 7;
    if (node >= n) return;
    unsigned int cn = cnts[node];
    int base = cursor[node] + bsum[node >> 8];
    int c = (int)(cn & 0xFFFFu);
    float s = (sub == 0) ? zs[node] : 0.0f;   // self loop (zs pre-scaled)
    for (int j = sub; j < c; j += 8) s += zs[col[base + j] & 0xFFFFu];
    s += __shfl_xor(s, 1);
    s += __shfl_xor(s, 2);
    s += __shfl_xor(s, 4);
    if (sub == 0) {
        float nd = rsqrtf((float)(cn & 0xFFFFu) + 1.0f);
        out[node] = nd * s + b2[0];
    }
}

extern "C" void kernel_launch(void* const* d_in, const int* in_sizes, int n_in,
                              void* d_out, int out_size, void* d_ws, size_t ws_size,
                              hipStream_t stream) {
    const float* x  = (const float*)d_in[0];
    const int*   ei = (const int*)d_in[1];
    const float* W1 = (const float*)d_in[2];
    const float* b1 = (const float*)d_in[3];
    const float* W2 = (const float*)d_in[4];
    const float* b2 = (const float*)d_in[5];
    float* out = (float*)d_out;

    const int n = in_sizes[0] / D;   // 50000
    const int e = in_sizes[1] / 2;   // 800000
    const int* src = ei;
    const int* dst = ei + e;

    const int nb = (n + 255) / 256;
    const int ce = (e + NCHUNK - 1) / NCHUNK;               // 12500
    const int W = (n + 1) / 2;                              // 25000 packed words
    const int npass = (n + NODE_TILE - 1) / NODE_TILE;      // 4
    const int gblocks = (n + 127) / 128;                    // 391

    // workspace layout -- no overlays
    char* ws = (char*)d_ws;
    int*   cursor = (int*)ws;    ws += sizeof(int) * (size_t)n;
    int*   bsum   = (int*)ws;    ws += sizeof(int) * (size_t)((nb + 255) & ~255);
    unsigned int* cnts = (unsigned int*)ws;  ws += sizeof(unsigned int) * (size_t)n;
    unsigned short* colpref = (unsigned short*)ws;
    ws += sizeof(unsigned short) * (size_t)NCHUNK * n;
    unsigned int* col = (unsigned int*)ws;   ws += sizeof(unsigned int) * (size_t)e;
    unsigned int* part_in = (unsigned int*)ws;
    ws += sizeof(unsigned int) * (size_t)NCHUNK * W;
    unsigned int* part_out = (unsigned int*)ws;
    ws += sizeof(unsigned int) * (size_t)NCHUNK * W;
    float* y  = (float*)ws;      ws += sizeof(float) * (size_t)n * D;
    float* zs = (float*)ws;      ws += sizeof(float) * (size_t)n;

    const int B = 256;
    const size_t smem = (size_t)W * sizeof(unsigned int);   // 100 KB (hist blocks)

    k_hist_gemm<<<2 * NCHUNK + gblocks, HTH, smem, stream>>>(
        src, dst, part_in, part_out, e, ce, W, x, W1, y, n);
    k_merge_scan<<<nb, 256, 0, stream>>>(part_in, part_out, colpref, cnts,
                                         cursor, bsum, n, W);
    k_scan_bsum<<<1, 256, 0, stream>>>(bsum, nb);
    k_bin_lds<<<dim3(NCHUNK, npass), HTH, 0, stream>>>(
        src, dst, cursor, bsum, colpref, cnts, col, e, n, ce);
    k_node<<<2048, B, 0, stream>>>(y, cursor, bsum, cnts, col, b1, W2, zs, n);
    k_out<<<((size_t)n * 8 + B - 1) / B, B, 0, stream>>>(zs, cursor, bsum, cnts,
                                                         col, b2, out, n);
}